// Round 15
// baseline (458.585 us; speedup 1.0000x reference)
//
#include <hip/hip_runtime.h>

typedef __bf16 bf16_t;
typedef __attribute__((ext_vector_type(4))) __bf16 bf16x4;
typedef __attribute__((ext_vector_type(8))) __bf16 bf16x8;
typedef __attribute__((ext_vector_type(4))) float f32x4;

#define SOFTMAX_SCALE 0.07216878364870322f   // 1/sqrt(192), folded into Q
#define NEG_MASK (-10000.0f)

// async global->LDS, 16B per lane, dest = wave-uniform base + lane*16 (linear)
__device__ __forceinline__ void async16(const bf16_t* g, bf16_t* l) {
  __builtin_amdgcn_global_load_lds(
      (const __attribute__((address_space(1))) unsigned int*)g,
      (__attribute__((address_space(3))) unsigned int*)l, 16, 0, 0);
}

// ---------------------------------------------------------------- mega prep
// One kernel, blockIdx-range dispatch:
//  [0,4608)    WUQ dequant -> WUQd (bf16)
//  [4608,5632) WUKV dequant, V-rows only (rows 128..255 per head) -> WUKVd
//  [5632,8704) Q f32->bf16 * SOFTMAX_SCALE -> Qb
//  [8704,8832) KV -> K4 chunk-major
//  [8832,9344) KV -> V4 chunk-major
//  [9344,9600) rope(PE) -> K4 kk=16,17
//  [9600,9856) WUKV (raw, K-rows) dequant+transpose -> Wv1t
__global__ void k_prep(const float* __restrict__ WUQ, const float* __restrict__ WUQs,
                       bf16_t* __restrict__ WUQd,
                       const float* __restrict__ WUKV, const float* __restrict__ WUKVs,
                       bf16_t* __restrict__ WUKVd, bf16_t* __restrict__ Wv1t,
                       const float* __restrict__ Q, bf16_t* __restrict__ Qb,
                       const float* __restrict__ KV, bf16_t* __restrict__ K4,
                       bf16_t* __restrict__ V4,
                       const float* __restrict__ PE, const float* __restrict__ idxt) {
  __shared__ bf16_t Lt[64][72];
  const int b = blockIdx.x;
  const int tid = threadIdx.x;

  if (b < 4608) {                      // WUQ dequant (full, 3072x1536)
    int i = (b * 256 + tid) * 4;
    int r = i / 1536, c = i % 1536;
    float s = WUQs[(r >> 7) * 12 + (c >> 7)];
    float4 w = *(const float4*)(WUQ + i);
    WUQd[i + 0] = (bf16_t)(w.x * s);
    WUQd[i + 1] = (bf16_t)(w.y * s);
    WUQd[i + 2] = (bf16_t)(w.z * s);
    WUQd[i + 3] = (bf16_t)(w.w * s);
  } else if (b < 5632) {               // WUKV dequant, V-rows only
    int i4 = ((b - 4608) * 256 + tid) * 4;       // 0..1M
    int h = i4 >> 16, within = i4 & 65535;
    int row = 128 + (within >> 9), col = within & 511;
    int R = h * 256 + row;
    float s = WUKVs[(R >> 7) * 4 + (col >> 7)];
    const float* src = WUKV + (size_t)R * 512 + col;
    float4 w = *(const float4*)src;
    bf16_t* dst = WUKVd + (size_t)R * 512 + col;
    dst[0] = (bf16_t)(w.x * s);
    dst[1] = (bf16_t)(w.y * s);
    dst[2] = (bf16_t)(w.z * s);
    dst[3] = (bf16_t)(w.w * s);
  } else if (b < 8704) {               // Q -> Qb (scale folded)
    int i = ((b - 5632) * 256 + tid) * 4;
    float4 v = *(const float4*)(Q + i);
    Qb[i + 0] = (bf16_t)(v.x * SOFTMAX_SCALE);
    Qb[i + 1] = (bf16_t)(v.y * SOFTMAX_SCALE);
    Qb[i + 2] = (bf16_t)(v.z * SOFTMAX_SCALE);
    Qb[i + 3] = (bf16_t)(v.w * SOFTMAX_SCALE);
  } else if (b < 8832) {               // KV -> K4
    int i = (b - 8704) * 256 + tid;    // 2048*16
    int c2 = i & 15, t = i >> 4;
    int tt = t >> 6, k = t & 63;
    const float* src = KV + (size_t)t * 512 + c2 * 32;
    bf16_t* dst = K4 + (size_t)tt * 36864 + c2 * 2048 + k * 8;
#pragma unroll
    for (int sub = 0; sub < 4; ++sub) {
      float4 u = *(const float4*)(src + sub * 8);
      float4 v = *(const float4*)(src + sub * 8 + 4);
      bf16x8 o;
      o[0] = (bf16_t)u.x; o[1] = (bf16_t)u.y; o[2] = (bf16_t)u.z; o[3] = (bf16_t)u.w;
      o[4] = (bf16_t)v.x; o[5] = (bf16_t)v.y; o[6] = (bf16_t)v.z; o[7] = (bf16_t)v.w;
      *(bf16x8*)(dst + sub * 512) = o;
    }
  } else if (b < 9344) {               // KV -> V4
    int i = (b - 8832) * 256 + tid;    // 131072
    int c = i & 511, a = i >> 9;
    int t0 = a * 8, tt = t0 >> 6;
    int key0 = t0 & 63, kk2 = key0 >> 5, sub = (key0 >> 3) & 3;
    bf16x8 o;
#pragma unroll
    for (int j = 0; j < 8; ++j)
      o[j] = (bf16_t)KV[(size_t)(t0 + j) * 512 + c];
    *(bf16x8*)(V4 + (size_t)tt * 32768 + kk2 * 16384 + sub * 4096 + c * 8) = o;
  } else if (b < 9600) {               // rope(PE) -> K4 kk=16,17
    int i = (b - 9344) * 256 + tid;    // 2048*32
    int t = i >> 5, j = i & 31;
    float a = idxt[t * 64 + j];
    float c1 = cosf(a), s1 = sinf(a);
    float e = PE[t * 64 + 2 * j], o = PE[t * 64 + 2 * j + 1];
    int tt = t >> 6, k = t & 63;
    bf16_t* base = K4 + (size_t)tt * 36864 + (j >> 3) * 512 + k * 8 + (j & 7);
    base[16 * 2048] = (bf16_t)(e * c1 - o * s1);   // d = 512+j
    base[17 * 2048] = (bf16_t)(o * c1 + e * s1);   // d = 544+j
  } else {                             // WUKV K-rows dequant+transpose -> Wv1t
    int bb = b - 9600;                 // 0..255
    int h = bb >> 4;
    int d0 = ((bb >> 3) & 1) * 64;
    int c0 = (bb & 7) * 64;
    float s = WUKVs[8 * h + (c0 >> 7)];   // rows h*256+d (d<128) -> scale row 2h
#pragma unroll
    for (int j = 0; j < 2; ++j) {
      int ch = tid * 2 + j, r = ch >> 3, c8 = ch & 7;
      const float* src = WUKV + (size_t)(h * 256 + d0 + r) * 512 + c0 + c8 * 8;
      float4 u = *(const float4*)src;
      float4 v = *(const float4*)(src + 4);
      bf16x8 o;
      o[0] = (bf16_t)(u.x * s); o[1] = (bf16_t)(u.y * s);
      o[2] = (bf16_t)(u.z * s); o[3] = (bf16_t)(u.w * s);
      o[4] = (bf16_t)(v.x * s); o[5] = (bf16_t)(v.y * s);
      o[6] = (bf16_t)(v.z * s); o[7] = (bf16_t)(v.w * s);
      *(bf16x8*)&Lt[r][c8 * 8] = o;
    }
    __syncthreads();
#pragma unroll
    for (int j = 0; j < 2; ++j) {
      int ch = tid * 2 + j, cc = ch >> 3, dd8 = ch & 7;
      bf16x8 o;
#pragma unroll
      for (int e = 0; e < 8; ++e) o[e] = Lt[dd8 * 8 + e][cc];
      *(bf16x8*)(Wv1t + (size_t)h * 65536 + (c0 + cc) * 128 + d0 + dd8 * 8) = o;
    }
  }
}

// ---------------------------------------------------------------- GEMM3 (universal)
// C = A * B^T, row-major bf16, batched via blockIdx.z. DMA staging with
// pre-swizzled global source + linear LDS + swizzled frag reads; double-
// buffered, 1 barrier/K-step.
// MODE: 0 = bf16 C, 1 = f32 C, 2 = bf16 C + fused q_pe rope into qfull.
template <int MODE>
__global__ __launch_bounds__(256) void k_gemm3(
    const bf16_t* __restrict__ A, int lda, long saz,
    const bf16_t* __restrict__ B, int ldb, long sbz,
    void* __restrict__ Cv, int ldc, long scz, int K,
    const float* __restrict__ idxt, bf16_t* __restrict__ qfull) {
  __shared__ __attribute__((aligned(16))) bf16_t At[2][8192];
  __shared__ __attribute__((aligned(16))) bf16_t Bt[2][8192];
  const int tid = threadIdx.x;
  const int lane = tid & 63;
  const int wv = tid >> 6;
  const int fr = lane & 15, fq = lane >> 4;
  const int wm = (wv & 1) * 64, wn = (wv >> 1) * 64;
  const int m0 = blockIdx.x * 128, n0 = blockIdx.y * 128;
  const bf16_t* Ab = A + (long)blockIdx.z * saz;
  const bf16_t* Bb = B + (long)blockIdx.z * sbz;

#define STAGE3(bufp, ks)                                                    \
  do {                                                                      \
    _Pragma("unroll") for (int i_ = 0; i_ < 4; ++i_) {                      \
      int ch_ = tid + i_ * 256;                                             \
      int ar_ = ch_ >> 3;                                                   \
      int c8_ = (ch_ & 7) ^ (ar_ & 7);                                      \
      async16(Ab + (size_t)(m0 + ar_) * lda + (ks) * 64 + c8_ * 8,          \
              At[bufp] + ch_ * 8);                                          \
      async16(Bb + (size_t)(n0 + ar_) * ldb + (ks) * 64 + c8_ * 8,          \
              Bt[bufp] + ch_ * 8);                                          \
    }                                                                       \
  } while (0)

  f32x4 acc[4][4] = {};
  const int nks = K >> 6;
  STAGE3(0, 0);
  for (int ks = 0; ks < nks; ++ks) {
    int buf = ks & 1;
    __syncthreads();           // drains vmcnt -> buf staged; prev reads done
    if (ks + 1 < nks) STAGE3(buf ^ 1, ks + 1);
#pragma unroll
    for (int kkl = 0; kkl < 2; ++kkl) {
      bf16x8 af[4], bfr[4];
#pragma unroll
      for (int m = 0; m < 4; ++m) {
        int row = wm + m * 16 + fr;
        af[m] = *(const bf16x8*)(At[buf] + (row * 8 + (((kkl * 4 + fq) ^ (row & 7)))) * 8);
      }
#pragma unroll
      for (int n = 0; n < 4; ++n) {
        int row = wn + n * 16 + fr;
        bfr[n] = *(const bf16x8*)(Bt[buf] + (row * 8 + (((kkl * 4 + fq) ^ (row & 7)))) * 8);
      }
#pragma unroll
      for (int m = 0; m < 4; ++m)
#pragma unroll
        for (int n = 0; n < 4; ++n)
          acc[m][n] = __builtin_amdgcn_mfma_f32_16x16x32_bf16(af[m], bfr[n], acc[m][n], 0, 0, 0);
    }
  }
#undef STAGE3
#pragma unroll
  for (int m = 0; m < 4; ++m) {
    int row0 = m0 + wm + m * 16 + fq * 4;
#pragma unroll
    for (int n = 0; n < 4; ++n) {
      int col = n0 + wn + n * 16 + fr;
#pragma unroll
      for (int i = 0; i < 4; ++i) {
        if (MODE == 1)
          ((float*)Cv)[(long)blockIdx.z * scz + (size_t)(row0 + i) * ldc + col] = acc[m][n][i];
        else
          ((bf16_t*)Cv)[(long)blockIdx.z * scz + (size_t)(row0 + i) * ldc + col] = (bf16_t)acc[m][n][i];
      }
      if (MODE == 2) {   // fused rope: pe cols (col%192 >= 128) -> qfull
        int head = col / 192;
        int within = col % 192;
        bool pe = within >= 128;
        int j = (within - 128) >> 1;
        bool evenc = (within & 1) == 0;
#pragma unroll
        for (int i = 0; i < 4; ++i) {
          int row = row0 + i;
          float v = acc[m][n][i];
          float other = __shfl_xor(v, 1);   // partner col (2j <-> 2j+1)
          if (pe) {
            float a = idxt[row * 64 + j];
            float c1 = cosf(a), s1 = sinf(a);
            bf16_t* dst = qfull + (size_t)head * 2048 * 576 + (size_t)row * 576 + 512;
            if (evenc) dst[j]      = (bf16_t)(v * c1 - other * s1);
            else       dst[32 + j] = (bf16_t)(v * c1 + other * s1);
          }
        }
      }
    }
  }
}

// ---------------------------------------------------------------- fused flash attention (MLA)
// (unchanged from R14: 126.4us)
__global__ __attribute__((amdgpu_flat_work_group_size(512, 512),
                          amdgpu_waves_per_eu(2, 2)))
void k_attn(const bf16_t* __restrict__ qfull,
            const bf16_t* __restrict__ K4,
            const bf16_t* __restrict__ V4,
            bf16_t* __restrict__ X) {
  __shared__ __attribute__((aligned(16))) bf16_t Kt[18 * 2048];  // 72KB
  __shared__ __attribute__((aligned(16))) bf16_t Vt[2 * 16384];  // 64KB
  __shared__ __attribute__((aligned(16))) bf16_t P[64 * 64];     // 8KB
  __shared__ __attribute__((aligned(16))) bf16_t Qpe[8 * 512];   // 8KB
  __shared__ float lred[4][64];

  const int tid = threadIdx.x;
  const int lane = tid & 63;
  const int w = tid >> 6;
  const int fr = lane & 15, fq = lane >> 4;
  const int h = blockIdx.x & 15;
  const int qt = 31 - (blockIdx.x >> 4);
  const int nt = qt + 1;
  const int rg = w >> 2;
  const int kq = w & 3;

  const bf16_t* qh = qfull + (size_t)h * 2048 * 576;
  bf16_t* Xh = X + (size_t)h * 2048 * 512;

  {
    int row = tid >> 3, sub = tid & 7;
    bf16x8 v = *(const bf16x8*)(qh + (size_t)(qt * 64 + row) * 576 + 512 + sub * 8);
    *(bf16x8*)(Qpe + sub * 512 + row * 8) = v;
  }

  bf16x8 qa[2][16];
  {
    const bf16_t* qb = qh + (size_t)(qt * 64 + rg * 32) * 576;
#pragma unroll
    for (int mf = 0; mf < 2; ++mf)
#pragma unroll
      for (int kk = 0; kk < 16; ++kk)
        qa[mf][kk] = *(const bf16x8*)(qb + (mf * 16 + fr) * 576 + kk * 32 + fq * 8);
  }

#pragma unroll
  for (int i = 0; i < 9; ++i) {
    int ck = w + 8 * i;
    async16(K4 + ck * 512 + lane * 8, Kt + ck * 512 + lane * 8);
  }

  f32x4 acc[2][8] = {};
  float lreg[2] = {0.f, 0.f};

  for (int t = 0; t < nt; ++t) {
    __syncthreads();   // B0: K(t) landed

    {
      const bf16_t* vsrc = V4 + (size_t)t * 32768;
#pragma unroll
      for (int i = 0; i < 8; ++i) {
        int cv = w + 8 * i;
        async16(vsrc + cv * 512 + lane * 8, Vt + cv * 512 + lane * 8);
      }
    }

    // ---- QK (swapped), 4 accumulator chains ----
    f32x4 sA[2] = {}, sB[2] = {};
    __builtin_amdgcn_s_setprio(1);
#pragma unroll
    for (int kk = 0; kk < 16; kk += 2) {
      bf16x8 kf0 = *(const bf16x8*)(Kt + kk * 2048 + fq * 512 + (kq * 16 + fr) * 8);
      bf16x8 kf1 = *(const bf16x8*)(Kt + (kk + 1) * 2048 + fq * 512 + (kq * 16 + fr) * 8);
      sA[0] = __builtin_amdgcn_mfma_f32_16x16x32_bf16(kf0, qa[0][kk], sA[0], 0, 0, 0);
      sA[1] = __builtin_amdgcn_mfma_f32_16x16x32_bf16(kf0, qa[1][kk], sA[1], 0, 0, 0);
      sB[0] = __builtin_amdgcn_mfma_f32_16x16x32_bf16(kf1, qa[0][kk + 1], sB[0], 0, 0, 0);
      sB[1] = __builtin_amdgcn_mfma_f32_16x16x32_bf16(kf1, qa[1][kk + 1], sB[1], 0, 0, 0);
    }
    {
      bf16x8 kf0 = *(const bf16x8*)(Kt + 16 * 2048 + fq * 512 + (kq * 16 + fr) * 8);
      bf16x8 kf1 = *(const bf16x8*)(Kt + 17 * 2048 + fq * 512 + (kq * 16 + fr) * 8);
      bf16x8 q00 = *(const bf16x8*)(Qpe + fq * 512 + (rg * 32 + fr) * 8);
      bf16x8 q01 = *(const bf16x8*)(Qpe + fq * 512 + (rg * 32 + 16 + fr) * 8);
      bf16x8 q10 = *(const bf16x8*)(Qpe + (4 + fq) * 512 + (rg * 32 + fr) * 8);
      bf16x8 q11 = *(const bf16x8*)(Qpe + (4 + fq) * 512 + (rg * 32 + 16 + fr) * 8);
      sA[0] = __builtin_amdgcn_mfma_f32_16x16x32_bf16(kf0, q00, sA[0], 0, 0, 0);
      sA[1] = __builtin_amdgcn_mfma_f32_16x16x32_bf16(kf0, q01, sA[1], 0, 0, 0);
      sB[0] = __builtin_amdgcn_mfma_f32_16x16x32_bf16(kf1, q10, sB[0], 0, 0, 0);
      sB[1] = __builtin_amdgcn_mfma_f32_16x16x32_bf16(kf1, q11, sB[1], 0, 0, 0);
    }
    __builtin_amdgcn_s_setprio(0);
    f32x4 s[2];
#pragma unroll
    for (int mf = 0; mf < 2; ++mf)
#pragma unroll
      for (int i = 0; i < 4; ++i) s[mf][i] = sA[mf][i] + sB[mf][i];

    bool diag = (t == qt);
#pragma unroll
    for (int mf = 0; mf < 2; ++mf) {
      int qrow = rg * 32 + mf * 16 + fr;
      if (diag) {
#pragma unroll
        for (int i = 0; i < 4; ++i) {
          int kcol = kq * 16 + fq * 4 + i;
          if (kcol > qrow) s[mf][i] += NEG_MASK;
        }
      }
      float p0 = __expf(s[mf][0]);
      float p1 = __expf(s[mf][1]);
      float p2 = __expf(s[mf][2]);
      float p3 = __expf(s[mf][3]);
      bf16x4 pk;
      pk[0] = (bf16_t)p0; pk[1] = (bf16_t)p1; pk[2] = (bf16_t)p2; pk[3] = (bf16_t)p3;
      int chunk = (kq * 2 + (fq >> 1)) ^ (qrow & 7);
      *(bf16x4*)(P + qrow * 64 + chunk * 8 + (fq & 1) * 4) = pk;
      lreg[mf] += (p0 + p1) + (p2 + p3);
    }
    __syncthreads();   // B1: P published; V landed; Kt reads done

    if (t + 1 < nt) {
      const bf16_t* ksrc = K4 + (size_t)(t + 1) * 36864;
#pragma unroll
      for (int i = 0; i < 9; ++i) {
        int ck = w + 8 * i;
        async16(ksrc + ck * 512 + lane * 8, Kt + ck * 512 + lane * 8);
      }
    }

    __builtin_amdgcn_s_setprio(1);
#pragma unroll
    for (int kk2 = 0; kk2 < 2; ++kk2) {
      bf16x8 pa[2];
#pragma unroll
      for (int mf = 0; mf < 2; ++mf) {
        int qrow = rg * 32 + mf * 16 + fr;
        pa[mf] = *(const bf16x8*)(P + qrow * 64 + (((kk2 * 4 + fq) ^ (qrow & 7)) * 8));
      }
#pragma unroll
      for (int nf = 0; nf < 8; ++nf) {
        bf16x8 vb = *(const bf16x8*)(Vt + kk2 * 16384 + fq * 4096 + (kq * 128 + nf * 16 + fr) * 8);
        acc[0][nf] = __builtin_amdgcn_mfma_f32_16x16x32_bf16(pa[0], vb, acc[0][nf], 0, 0, 0);
        acc[1][nf] = __builtin_amdgcn_mfma_f32_16x16x32_bf16(pa[1], vb, acc[1][nf], 0, 0, 0);
      }
    }
    __builtin_amdgcn_s_setprio(0);
  }

#pragma unroll
  for (int mf = 0; mf < 2; ++mf) {
    float lw = lreg[mf];
    lw += __shfl_xor(lw, 16);
    lw += __shfl_xor(lw, 32);
    if (fq == 0) lred[kq][rg * 32 + mf * 16 + fr] = lw;
  }
  __syncthreads();

  {
    bf16_t* XT = Kt;
#pragma unroll
    for (int mf = 0; mf < 2; ++mf)
#pragma unroll
      for (int i = 0; i < 4; ++i) {
        int row = rg * 32 + mf * 16 + fq * 4 + i;
        float invl = 1.0f / ((lred[0][row] + lred[1][row]) + (lred[2][row] + lred[3][row]));
#pragma unroll
        for (int nf = 0; nf < 8; ++nf)
          XT[row * 512 + kq * 128 + nf * 16 + fr] = (bf16_t)(acc[mf][nf][i] * invl);
      }
  }
  __syncthreads();
#pragma unroll
  for (int it = 0; it < 8; ++it) {
    int id = tid + it * 512;
    int row = id >> 6, j = id & 63;
    *(bf16x8*)(Xh + (size_t)(qt * 64 + row) * 512 + j * 8) = *(const bf16x8*)(Kt + row * 512 + j * 8);
  }
}

// ---------------------------------------------------------------- launcher

extern "C" void kernel_launch(void* const* d_in, const int* in_sizes, int n_in,
                              void* d_out, int out_size, void* d_ws, size_t ws_size,
                              hipStream_t stream) {
  (void)in_sizes; (void)n_in; (void)out_size; (void)ws_size;
  const float* WUQ   = (const float*)d_in[0];
  const float* WUQs  = (const float*)d_in[1];
  const float* WUKV  = (const float*)d_in[2];
  const float* WUKVs = (const float*)d_in[3];
  const float* Q     = (const float*)d_in[4];
  const float* KV    = (const float*)d_in[5];
  const float* PE    = (const float*)d_in[6];
  const float* idxt  = (const float*)d_in[9];
  float* out = (float*)d_out;

  char* ws = (char*)d_ws;
  size_t off = 0;
  auto alloc = [&](size_t n) -> char* {
    char* p = ws + off;
    off += (n + 255) & ~(size_t)255;
    return p;
  };
  bf16_t* WUQd  = (bf16_t*)alloc((size_t)3072 * 1536 * 2);
  bf16_t* Qb    = (bf16_t*)alloc((size_t)2048 * 1536 * 2);
  bf16_t* WUKVd = (bf16_t*)alloc((size_t)4096 * 512 * 2);
  bf16_t* Wv1t  = (bf16_t*)alloc((size_t)16 * 512 * 128 * 2);
  bf16_t* qbuf  = (bf16_t*)alloc((size_t)2048 * 3072 * 2);
  bf16_t* K4    = (bf16_t*)alloc((size_t)32 * 36864 * 2);
  bf16_t* V4    = (bf16_t*)alloc((size_t)32 * 32768 * 2);
  bf16_t* qfull = (bf16_t*)alloc((size_t)16 * 2048 * 576 * 2);
  bf16_t* Xb    = (bf16_t*)alloc((size_t)16 * 2048 * 512 * 2);

  // 1: all preps fused (range-dispatched)
  k_prep<<<9856, 256, 0, stream>>>(WUQ, WUQs, WUQd, WUKV, WUKVs, WUKVd, Wv1t,
                                   Q, Qb, KV, K4, V4, PE, idxt);
  // 2: q = Qb @ WUQd^T -> qbuf, with fused q_pe rope -> qfull[...][512..]
  k_gemm3<2><<<dim3(16, 24, 1), 256, 0, stream>>>(Qb, 1536, 0, WUQd, 1536, 0,
                                                  qbuf, 3072, 0, 1536, idxt, qfull);
  // 3: q_lat[h] = q_nope[h] @ Wv1t[h]^T -> qfull[h][t][0..511]
  k_gemm3<0><<<dim3(16, 4, 16), 256, 0, stream>>>(qbuf, 3072, 192, Wv1t, 128, (long)512 * 128,
                                                  qfull, 576, (long)2048 * 576, 128,
                                                  nullptr, nullptr);
  // 4: attention
  k_attn<<<dim3(512), dim3(512), 0, stream>>>(qfull, K4, V4, Xb);
  // 5: out[t][h*128+d] = X[h] @ W3_v[h]^T
  k_gemm3<1><<<dim3(16, 1, 16), 256, 0, stream>>>(Xb, 512, (long)2048 * 512,
                                                  WUKVd + 128 * 512, 512, (long)256 * 512,
                                                  out, 2048, 128, 512, nullptr, nullptr);
}

// Round 16
// 194.408 us; speedup vs baseline: 2.3589x; 2.3589x over previous
//
#include <hip/hip_runtime.h>

typedef __bf16 bf16_t;
typedef __attribute__((ext_vector_type(4))) __bf16 bf16x4;
typedef __attribute__((ext_vector_type(8))) __bf16 bf16x8;
typedef __attribute__((ext_vector_type(4))) float f32x4;

#define SOFTMAX_SCALE 0.07216878364870322f   // 1/sqrt(192), folded into Q
#define NEG_MASK (-10000.0f)

// async global->LDS, 16B per lane, dest = wave-uniform base + lane*16 (linear)
__device__ __forceinline__ void async16(const bf16_t* g, bf16_t* l) {
  __builtin_amdgcn_global_load_lds(
      (const __attribute__((address_space(1))) unsigned int*)g,
      (__attribute__((address_space(3))) unsigned int*)l, 16, 0, 0);
}

// ---------------------------------------------------------------- mega prep
// One kernel, blockIdx-range dispatch:
//  [0,4608)    WUQ dequant -> WUQd (bf16)
//  [4608,5632) WUKV dequant, V-rows only (rows 128..255 per head) -> WUKVd
//  [5632,8704) Q f32->bf16 * SOFTMAX_SCALE -> Qb
//  [8704,8832) KV -> K4 chunk-major
//  [8832,9344) KV -> V4 chunk-major
//  [9344,9600) rope(PE) -> K4 kk=16,17
//  [9600,9856) WUKV (raw, K-rows) dequant+transpose -> Wv1t
__global__ void k_prep(const float* __restrict__ WUQ, const float* __restrict__ WUQs,
                       bf16_t* __restrict__ WUQd,
                       const float* __restrict__ WUKV, const float* __restrict__ WUKVs,
                       bf16_t* __restrict__ WUKVd, bf16_t* __restrict__ Wv1t,
                       const float* __restrict__ Q, bf16_t* __restrict__ Qb,
                       const float* __restrict__ KV, bf16_t* __restrict__ K4,
                       bf16_t* __restrict__ V4,
                       const float* __restrict__ PE, const float* __restrict__ idxt) {
  __shared__ bf16_t Lt[64][72];
  const int b = blockIdx.x;
  const int tid = threadIdx.x;

  if (b < 4608) {                      // WUQ dequant (full, 3072x1536)
    int i = (b * 256 + tid) * 4;
    int r = i / 1536, c = i % 1536;
    float s = WUQs[(r >> 7) * 12 + (c >> 7)];
    float4 w = *(const float4*)(WUQ + i);
    WUQd[i + 0] = (bf16_t)(w.x * s);
    WUQd[i + 1] = (bf16_t)(w.y * s);
    WUQd[i + 2] = (bf16_t)(w.z * s);
    WUQd[i + 3] = (bf16_t)(w.w * s);
  } else if (b < 5632) {               // WUKV dequant, V-rows only
    int i4 = ((b - 4608) * 256 + tid) * 4;       // 0..1M
    int h = i4 >> 16, within = i4 & 65535;
    int row = 128 + (within >> 9), col = within & 511;
    int R = h * 256 + row;
    float s = WUKVs[(R >> 7) * 4 + (col >> 7)];
    const float* src = WUKV + (size_t)R * 512 + col;
    float4 w = *(const float4*)src;
    bf16_t* dst = WUKVd + (size_t)R * 512 + col;
    dst[0] = (bf16_t)(w.x * s);
    dst[1] = (bf16_t)(w.y * s);
    dst[2] = (bf16_t)(w.z * s);
    dst[3] = (bf16_t)(w.w * s);
  } else if (b < 8704) {               // Q -> Qb (scale folded)
    int i = ((b - 5632) * 256 + tid) * 4;
    float4 v = *(const float4*)(Q + i);
    Qb[i + 0] = (bf16_t)(v.x * SOFTMAX_SCALE);
    Qb[i + 1] = (bf16_t)(v.y * SOFTMAX_SCALE);
    Qb[i + 2] = (bf16_t)(v.z * SOFTMAX_SCALE);
    Qb[i + 3] = (bf16_t)(v.w * SOFTMAX_SCALE);
  } else if (b < 8832) {               // KV -> K4
    int i = (b - 8704) * 256 + tid;    // 2048*16
    int c2 = i & 15, t = i >> 4;
    int tt = t >> 6, k = t & 63;
    const float* src = KV + (size_t)t * 512 + c2 * 32;
    bf16_t* dst = K4 + (size_t)tt * 36864 + c2 * 2048 + k * 8;
#pragma unroll
    for (int sub = 0; sub < 4; ++sub) {
      float4 u = *(const float4*)(src + sub * 8);
      float4 v = *(const float4*)(src + sub * 8 + 4);
      bf16x8 o;
      o[0] = (bf16_t)u.x; o[1] = (bf16_t)u.y; o[2] = (bf16_t)u.z; o[3] = (bf16_t)u.w;
      o[4] = (bf16_t)v.x; o[5] = (bf16_t)v.y; o[6] = (bf16_t)v.z; o[7] = (bf16_t)v.w;
      *(bf16x8*)(dst + sub * 512) = o;
    }
  } else if (b < 9344) {               // KV -> V4
    int i = (b - 8832) * 256 + tid;    // 131072
    int c = i & 511, a = i >> 9;
    int t0 = a * 8, tt = t0 >> 6;
    int key0 = t0 & 63, kk2 = key0 >> 5, sub = (key0 >> 3) & 3;
    bf16x8 o;
#pragma unroll
    for (int j = 0; j < 8; ++j)
      o[j] = (bf16_t)KV[(size_t)(t0 + j) * 512 + c];
    *(bf16x8*)(V4 + (size_t)tt * 32768 + kk2 * 16384 + sub * 4096 + c * 8) = o;
  } else if (b < 9600) {               // rope(PE) -> K4 kk=16,17
    int i = (b - 9344) * 256 + tid;    // 2048*32
    int t = i >> 5, j = i & 31;
    float a = idxt[t * 64 + j];
    float c1 = cosf(a), s1 = sinf(a);
    float e = PE[t * 64 + 2 * j], o = PE[t * 64 + 2 * j + 1];
    int tt = t >> 6, k = t & 63;
    bf16_t* base = K4 + (size_t)tt * 36864 + (j >> 3) * 512 + k * 8 + (j & 7);
    base[16 * 2048] = (bf16_t)(e * c1 - o * s1);   // d = 512+j
    base[17 * 2048] = (bf16_t)(o * c1 + e * s1);   // d = 544+j
  } else {                             // WUKV K-rows dequant+transpose -> Wv1t
    int bb = b - 9600;                 // 0..255
    int h = bb >> 4;
    int d0 = ((bb >> 3) & 1) * 64;
    int c0 = (bb & 7) * 64;
    float s = WUKVs[8 * h + (c0 >> 7)];   // rows h*256+d (d<128) -> scale row 2h
#pragma unroll
    for (int j = 0; j < 2; ++j) {
      int ch = tid * 2 + j, r = ch >> 3, c8 = ch & 7;
      const float* src = WUKV + (size_t)(h * 256 + d0 + r) * 512 + c0 + c8 * 8;
      float4 u = *(const float4*)src;
      float4 v = *(const float4*)(src + 4);
      bf16x8 o;
      o[0] = (bf16_t)(u.x * s); o[1] = (bf16_t)(u.y * s);
      o[2] = (bf16_t)(u.z * s); o[3] = (bf16_t)(u.w * s);
      o[4] = (bf16_t)(v.x * s); o[5] = (bf16_t)(v.y * s);
      o[6] = (bf16_t)(v.z * s); o[7] = (bf16_t)(v.w * s);
      *(bf16x8*)&Lt[r][c8 * 8] = o;
    }
    __syncthreads();
#pragma unroll
    for (int j = 0; j < 2; ++j) {
      int ch = tid * 2 + j, cc = ch >> 3, dd8 = ch & 7;
      bf16x8 o;
#pragma unroll
      for (int e = 0; e < 8; ++e) o[e] = Lt[dd8 * 8 + e][cc];
      *(bf16x8*)(Wv1t + (size_t)h * 65536 + (c0 + cc) * 128 + d0 + dd8 * 8) = o;
    }
  }
}

// rope on q_pe -> qfull[h][t][512..575]  (input already carries SOFTMAX_SCALE)
__global__ void k_q_rope(const bf16_t* __restrict__ q, const float* __restrict__ idxt,
                         bf16_t* __restrict__ qfull) {
  int i = blockIdx.x * 256 + threadIdx.x;        // 2048*16*32
  int j = i & 31, h = (i >> 5) & 15, t = i >> 9;
  float a = idxt[t * 64 + j];
  float c1 = cosf(a), s1 = sinf(a);
  const bf16_t* src = q + t * 3072 + h * 192 + 128;
  float e = (float)src[2 * j], o = (float)src[2 * j + 1];
  bf16_t* dst = qfull + (size_t)h * 2048 * 576 + t * 576 + 512;
  dst[j]      = (bf16_t)(e * c1 - o * s1);
  dst[32 + j] = (bf16_t)(o * c1 + e * s1);
}

// ---------------------------------------------------------------- GEMM3 (universal)
// C = A * B^T, row-major bf16, batched via blockIdx.z. DMA staging with
// pre-swizzled global source + linear LDS + swizzled frag reads; double-
// buffered, 1 barrier/K-step.  (R14 form -- no fused epilogues.)
template <int OUT_F32>
__global__ __launch_bounds__(256) void k_gemm3(
    const bf16_t* __restrict__ A, int lda, long saz,
    const bf16_t* __restrict__ B, int ldb, long sbz,
    void* __restrict__ Cv, int ldc, long scz, int K) {
  __shared__ __attribute__((aligned(16))) bf16_t At[2][8192];
  __shared__ __attribute__((aligned(16))) bf16_t Bt[2][8192];
  const int tid = threadIdx.x;
  const int lane = tid & 63;
  const int wv = tid >> 6;
  const int fr = lane & 15, fq = lane >> 4;
  const int wm = (wv & 1) * 64, wn = (wv >> 1) * 64;
  const int m0 = blockIdx.x * 128, n0 = blockIdx.y * 128;
  const bf16_t* Ab = A + (long)blockIdx.z * saz;
  const bf16_t* Bb = B + (long)blockIdx.z * sbz;

#define STAGE3(bufp, ks)                                                    \
  do {                                                                      \
    _Pragma("unroll") for (int i_ = 0; i_ < 4; ++i_) {                      \
      int ch_ = tid + i_ * 256;                                             \
      int ar_ = ch_ >> 3;                                                   \
      int c8_ = (ch_ & 7) ^ (ar_ & 7);                                      \
      async16(Ab + (size_t)(m0 + ar_) * lda + (ks) * 64 + c8_ * 8,          \
              At[bufp] + ch_ * 8);                                          \
      async16(Bb + (size_t)(n0 + ar_) * ldb + (ks) * 64 + c8_ * 8,          \
              Bt[bufp] + ch_ * 8);                                          \
    }                                                                       \
  } while (0)

  f32x4 acc[4][4] = {};
  const int nks = K >> 6;
  STAGE3(0, 0);
  for (int ks = 0; ks < nks; ++ks) {
    int buf = ks & 1;
    __syncthreads();           // drains vmcnt -> buf staged; prev reads done
    if (ks + 1 < nks) STAGE3(buf ^ 1, ks + 1);
#pragma unroll
    for (int kkl = 0; kkl < 2; ++kkl) {
      bf16x8 af[4], bfr[4];
#pragma unroll
      for (int m = 0; m < 4; ++m) {
        int row = wm + m * 16 + fr;
        af[m] = *(const bf16x8*)(At[buf] + (row * 8 + (((kkl * 4 + fq) ^ (row & 7)))) * 8);
      }
#pragma unroll
      for (int n = 0; n < 4; ++n) {
        int row = wn + n * 16 + fr;
        bfr[n] = *(const bf16x8*)(Bt[buf] + (row * 8 + (((kkl * 4 + fq) ^ (row & 7)))) * 8);
      }
#pragma unroll
      for (int m = 0; m < 4; ++m)
#pragma unroll
        for (int n = 0; n < 4; ++n)
          acc[m][n] = __builtin_amdgcn_mfma_f32_16x16x32_bf16(af[m], bfr[n], acc[m][n], 0, 0, 0);
    }
  }
#undef STAGE3
#pragma unroll
  for (int m = 0; m < 4; ++m) {
    int row = m0 + wm + m * 16 + fq * 4;
#pragma unroll
    for (int n = 0; n < 4; ++n) {
      int col = n0 + wn + n * 16 + fr;
#pragma unroll
      for (int i = 0; i < 4; ++i) {
        if (OUT_F32)
          ((float*)Cv)[(long)blockIdx.z * scz + (size_t)(row + i) * ldc + col] = acc[m][n][i];
        else
          ((bf16_t*)Cv)[(long)blockIdx.z * scz + (size_t)(row + i) * ldc + col] = (bf16_t)acc[m][n][i];
      }
    }
  }
}

// ---------------------------------------------------------------- fused flash attention (MLA)
// (unchanged from R14: 126.4us)
__global__ __attribute__((amdgpu_flat_work_group_size(512, 512),
                          amdgpu_waves_per_eu(2, 2)))
void k_attn(const bf16_t* __restrict__ qfull,
            const bf16_t* __restrict__ K4,
            const bf16_t* __restrict__ V4,
            bf16_t* __restrict__ X) {
  __shared__ __attribute__((aligned(16))) bf16_t Kt[18 * 2048];  // 72KB
  __shared__ __attribute__((aligned(16))) bf16_t Vt[2 * 16384];  // 64KB
  __shared__ __attribute__((aligned(16))) bf16_t P[64 * 64];     // 8KB
  __shared__ __attribute__((aligned(16))) bf16_t Qpe[8 * 512];   // 8KB
  __shared__ float lred[4][64];

  const int tid = threadIdx.x;
  const int lane = tid & 63;
  const int w = tid >> 6;
  const int fr = lane & 15, fq = lane >> 4;
  const int h = blockIdx.x & 15;
  const int qt = 31 - (blockIdx.x >> 4);
  const int nt = qt + 1;
  const int rg = w >> 2;
  const int kq = w & 3;

  const bf16_t* qh = qfull + (size_t)h * 2048 * 576;
  bf16_t* Xh = X + (size_t)h * 2048 * 512;

  {
    int row = tid >> 3, sub = tid & 7;
    bf16x8 v = *(const bf16x8*)(qh + (size_t)(qt * 64 + row) * 576 + 512 + sub * 8);
    *(bf16x8*)(Qpe + sub * 512 + row * 8) = v;
  }

  bf16x8 qa[2][16];
  {
    const bf16_t* qb = qh + (size_t)(qt * 64 + rg * 32) * 576;
#pragma unroll
    for (int mf = 0; mf < 2; ++mf)
#pragma unroll
      for (int kk = 0; kk < 16; ++kk)
        qa[mf][kk] = *(const bf16x8*)(qb + (mf * 16 + fr) * 576 + kk * 32 + fq * 8);
  }

#pragma unroll
  for (int i = 0; i < 9; ++i) {
    int ck = w + 8 * i;
    async16(K4 + ck * 512 + lane * 8, Kt + ck * 512 + lane * 8);
  }

  f32x4 acc[2][8] = {};
  float lreg[2] = {0.f, 0.f};

  for (int t = 0; t < nt; ++t) {
    __syncthreads();   // B0: K(t) landed

    {
      const bf16_t* vsrc = V4 + (size_t)t * 32768;
#pragma unroll
      for (int i = 0; i < 8; ++i) {
        int cv = w + 8 * i;
        async16(vsrc + cv * 512 + lane * 8, Vt + cv * 512 + lane * 8);
      }
    }

    // ---- QK (swapped), 4 accumulator chains ----
    f32x4 sA[2] = {}, sB[2] = {};
    __builtin_amdgcn_s_setprio(1);
#pragma unroll
    for (int kk = 0; kk < 16; kk += 2) {
      bf16x8 kf0 = *(const bf16x8*)(Kt + kk * 2048 + fq * 512 + (kq * 16 + fr) * 8);
      bf16x8 kf1 = *(const bf16x8*)(Kt + (kk + 1) * 2048 + fq * 512 + (kq * 16 + fr) * 8);
      sA[0] = __builtin_amdgcn_mfma_f32_16x16x32_bf16(kf0, qa[0][kk], sA[0], 0, 0, 0);
      sA[1] = __builtin_amdgcn_mfma_f32_16x16x32_bf16(kf0, qa[1][kk], sA[1], 0, 0, 0);
      sB[0] = __builtin_amdgcn_mfma_f32_16x16x32_bf16(kf1, qa[0][kk + 1], sB[0], 0, 0, 0);
      sB[1] = __builtin_amdgcn_mfma_f32_16x16x32_bf16(kf1, qa[1][kk + 1], sB[1], 0, 0, 0);
    }
    {
      bf16x8 kf0 = *(const bf16x8*)(Kt + 16 * 2048 + fq * 512 + (kq * 16 + fr) * 8);
      bf16x8 kf1 = *(const bf16x8*)(Kt + 17 * 2048 + fq * 512 + (kq * 16 + fr) * 8);
      bf16x8 q00 = *(const bf16x8*)(Qpe + fq * 512 + (rg * 32 + fr) * 8);
      bf16x8 q01 = *(const bf16x8*)(Qpe + fq * 512 + (rg * 32 + 16 + fr) * 8);
      bf16x8 q10 = *(const bf16x8*)(Qpe + (4 + fq) * 512 + (rg * 32 + fr) * 8);
      bf16x8 q11 = *(const bf16x8*)(Qpe + (4 + fq) * 512 + (rg * 32 + 16 + fr) * 8);
      sA[0] = __builtin_amdgcn_mfma_f32_16x16x32_bf16(kf0, q00, sA[0], 0, 0, 0);
      sA[1] = __builtin_amdgcn_mfma_f32_16x16x32_bf16(kf0, q01, sA[1], 0, 0, 0);
      sB[0] = __builtin_amdgcn_mfma_f32_16x16x32_bf16(kf1, q10, sB[0], 0, 0, 0);
      sB[1] = __builtin_amdgcn_mfma_f32_16x16x32_bf16(kf1, q11, sB[1], 0, 0, 0);
    }
    __builtin_amdgcn_s_setprio(0);
    f32x4 s[2];
#pragma unroll
    for (int mf = 0; mf < 2; ++mf)
#pragma unroll
      for (int i = 0; i < 4; ++i) s[mf][i] = sA[mf][i] + sB[mf][i];

    bool diag = (t == qt);
#pragma unroll
    for (int mf = 0; mf < 2; ++mf) {
      int qrow = rg * 32 + mf * 16 + fr;
      if (diag) {
#pragma unroll
        for (int i = 0; i < 4; ++i) {
          int kcol = kq * 16 + fq * 4 + i;
          if (kcol > qrow) s[mf][i] += NEG_MASK;
        }
      }
      float p0 = __expf(s[mf][0]);
      float p1 = __expf(s[mf][1]);
      float p2 = __expf(s[mf][2]);
      float p3 = __expf(s[mf][3]);
      bf16x4 pk;
      pk[0] = (bf16_t)p0; pk[1] = (bf16_t)p1; pk[2] = (bf16_t)p2; pk[3] = (bf16_t)p3;
      int chunk = (kq * 2 + (fq >> 1)) ^ (qrow & 7);
      *(bf16x4*)(P + qrow * 64 + chunk * 8 + (fq & 1) * 4) = pk;
      lreg[mf] += (p0 + p1) + (p2 + p3);
    }
    __syncthreads();   // B1: P published; V landed; Kt reads done

    if (t + 1 < nt) {
      const bf16_t* ksrc = K4 + (size_t)(t + 1) * 36864;
#pragma unroll
      for (int i = 0; i < 9; ++i) {
        int ck = w + 8 * i;
        async16(ksrc + ck * 512 + lane * 8, Kt + ck * 512 + lane * 8);
      }
    }

    __builtin_amdgcn_s_setprio(1);
#pragma unroll
    for (int kk2 = 0; kk2 < 2; ++kk2) {
      bf16x8 pa[2];
#pragma unroll
      for (int mf = 0; mf < 2; ++mf) {
        int qrow = rg * 32 + mf * 16 + fr;
        pa[mf] = *(const bf16x8*)(P + qrow * 64 + (((kk2 * 4 + fq) ^ (qrow & 7)) * 8));
      }
#pragma unroll
      for (int nf = 0; nf < 8; ++nf) {
        bf16x8 vb = *(const bf16x8*)(Vt + kk2 * 16384 + fq * 4096 + (kq * 128 + nf * 16 + fr) * 8);
        acc[0][nf] = __builtin_amdgcn_mfma_f32_16x16x32_bf16(pa[0], vb, acc[0][nf], 0, 0, 0);
        acc[1][nf] = __builtin_amdgcn_mfma_f32_16x16x32_bf16(pa[1], vb, acc[1][nf], 0, 0, 0);
      }
    }
    __builtin_amdgcn_s_setprio(0);
  }

#pragma unroll
  for (int mf = 0; mf < 2; ++mf) {
    float lw = lreg[mf];
    lw += __shfl_xor(lw, 16);
    lw += __shfl_xor(lw, 32);
    if (fq == 0) lred[kq][rg * 32 + mf * 16 + fr] = lw;
  }
  __syncthreads();

  {
    bf16_t* XT = Kt;
#pragma unroll
    for (int mf = 0; mf < 2; ++mf)
#pragma unroll
      for (int i = 0; i < 4; ++i) {
        int row = rg * 32 + mf * 16 + fq * 4 + i;
        float invl = 1.0f / ((lred[0][row] + lred[1][row]) + (lred[2][row] + lred[3][row]));
#pragma unroll
        for (int nf = 0; nf < 8; ++nf)
          XT[row * 512 + kq * 128 + nf * 16 + fr] = (bf16_t)(acc[mf][nf][i] * invl);
      }
  }
  __syncthreads();
#pragma unroll
  for (int it = 0; it < 8; ++it) {
    int id = tid + it * 512;
    int row = id >> 6, j = id & 63;
    *(bf16x8*)(Xh + (size_t)(qt * 64 + row) * 512 + j * 8) = *(const bf16x8*)(Kt + row * 512 + j * 8);
  }
}

// ---------------------------------------------------------------- launcher

extern "C" void kernel_launch(void* const* d_in, const int* in_sizes, int n_in,
                              void* d_out, int out_size, void* d_ws, size_t ws_size,
                              hipStream_t stream) {
  (void)in_sizes; (void)n_in; (void)out_size; (void)ws_size;
  const float* WUQ   = (const float*)d_in[0];
  const float* WUQs  = (const float*)d_in[1];
  const float* WUKV  = (const float*)d_in[2];
  const float* WUKVs = (const float*)d_in[3];
  const float* Q     = (const float*)d_in[4];
  const float* KV    = (const float*)d_in[5];
  const float* PE    = (const float*)d_in[6];
  const float* idxt  = (const float*)d_in[9];
  float* out = (float*)d_out;

  char* ws = (char*)d_ws;
  size_t off = 0;
  auto alloc = [&](size_t n) -> char* {
    char* p = ws + off;
    off += (n + 255) & ~(size_t)255;
    return p;
  };
  bf16_t* WUQd  = (bf16_t*)alloc((size_t)3072 * 1536 * 2);
  bf16_t* Qb    = (bf16_t*)alloc((size_t)2048 * 1536 * 2);
  bf16_t* WUKVd = (bf16_t*)alloc((size_t)4096 * 512 * 2);
  bf16_t* Wv1t  = (bf16_t*)alloc((size_t)16 * 512 * 128 * 2);
  bf16_t* qbuf  = (bf16_t*)alloc((size_t)2048 * 3072 * 2);
  bf16_t* K4    = (bf16_t*)alloc((size_t)32 * 36864 * 2);
  bf16_t* V4    = (bf16_t*)alloc((size_t)32 * 32768 * 2);
  bf16_t* qfull = (bf16_t*)alloc((size_t)16 * 2048 * 576 * 2);
  bf16_t* Xb    = (bf16_t*)alloc((size_t)16 * 2048 * 512 * 2);

  // 1: all preps fused (range-dispatched)
  k_prep<<<9856, 256, 0, stream>>>(WUQ, WUQs, WUQd, WUKV, WUKVs, WUKVd, Wv1t,
                                   Q, Qb, KV, K4, V4, PE, idxt);
  // 2: q = Qb @ WUQd^T -> qbuf [2048, 3072] bf16 (carries SOFTMAX_SCALE)
  k_gemm3<0><<<dim3(16, 24, 1), 256, 0, stream>>>(Qb, 1536, 0, WUQd, 1536, 0,
                                                  qbuf, 3072, 0, 1536);
  // 3: rope on q_pe -> qfull[...][512..]
  k_q_rope<<<4096, 256, 0, stream>>>(qbuf, idxt, qfull);
  // 4: q_lat[h] = q_nope[h] @ Wv1t[h]^T -> qfull[h][t][0..511]
  k_gemm3<0><<<dim3(16, 4, 16), 256, 0, stream>>>(qbuf, 3072, 192, Wv1t, 128, (long)512 * 128,
                                                  qfull, 576, (long)2048 * 576, 128);
  // 5: attention
  k_attn<<<dim3(512), dim3(512), 0, stream>>>(qfull, K4, V4, Xb);
  // 6: out[t][h*128+d] = X[h] @ W3_v[h]^T
  k_gemm3<1><<<dim3(16, 1, 16), 256, 0, stream>>>(Xb, 512, (long)2048 * 512,
                                                  WUKVd + 128 * 512, 512, (long)256 * 512,
                                                  out, 2048, 128, 512);
}